// Round 1
// baseline (641.407 us; speedup 1.0000x reference)
//
#include <hip/hip_runtime.h>

#define NROW 27
#define EDIM 5120
#define QKVDIM 15360
#define HD 1280

// ---------------------------------------------------------------------------
// Skinny GEMM: C[27, Ntot] += (X[27,K] @ W[Ntot,K]^T) [* scale, + bias at ky==0]
// K-split across blockIdx.y, fp32 atomic accumulate into zeroed C.
// Block tile: M=32 (27 real) x N=256, 256 threads, micro-tile 8m x 4n.
// LDS tiles stored k-major so the inner loop is 3x ds_read_b128 -> 32 FMA.
// ---------------------------------------------------------------------------
#define BN 256
#define BM 32
#define KC 32

__global__ __launch_bounds__(256)
void gemm_tall(const float* __restrict__ X, const float* __restrict__ W,
               float* __restrict__ C, const float* __restrict__ bias,
               const int* __restrict__ hz, int K, int Ntot, int Kc)
{
    __shared__ float Ws[KC][BN];   // 32 KB, [kc][n]
    __shared__ float Xs[KC][BM];   // 4 KB,  [kc][m]

    const int tid = threadIdx.x;
    const int n0  = blockIdx.x * BN;
    const int k0  = blockIdx.y * Kc;

    const int tn = tid & 63;   // n = 4*tn (0..255)
    const int tm = tid >> 6;   // m = 8*tm (0..31)

    float acc[8][4];
    #pragma unroll
    for (int mi = 0; mi < 8; ++mi)
        #pragma unroll
        for (int ni = 0; ni < 4; ++ni) acc[mi][ni] = 0.f;

    // W loader: thread tid owns row n0+tid, 8 float4 along k per chunk.
    const float* wrow = W + (size_t)(n0 + tid) * K + k0;
    // X loader: thread owns (m = tid&31, k4 = tid>>5), 1 float4 per chunk.
    const int  mx  = tid & 31;
    const int  k4x = tid >> 5;
    const bool xok = (mx < NROW);
    const float* xrow = X + (size_t)(xok ? mx : 0) * K + k0 + 4 * k4x;

    for (int kb = 0; kb < Kc; kb += KC) {
        #pragma unroll
        for (int it = 0; it < 8; ++it) {
            float4 w4 = *(const float4*)(wrow + 4 * it);
            // write bank = tid%32 -> 2-way across a wave (free)
            Ws[4*it+0][tid] = w4.x;
            Ws[4*it+1][tid] = w4.y;
            Ws[4*it+2][tid] = w4.z;
            Ws[4*it+3][tid] = w4.w;
        }
        float4 x4 = xok ? *(const float4*)xrow : make_float4(0.f, 0.f, 0.f, 0.f);
        Xs[4*k4x+0][mx] = x4.x;
        Xs[4*k4x+1][mx] = x4.y;
        Xs[4*k4x+2][mx] = x4.z;
        Xs[4*k4x+3][mx] = x4.w;
        __syncthreads();

        #pragma unroll 8
        for (int kc = 0; kc < KC; ++kc) {
            float4 wv = *(const float4*)&Ws[kc][4 * tn];      // 1KB span, conflict-free
            float4 xa = *(const float4*)&Xs[kc][8 * tm];      // wave-broadcast
            float4 xb = *(const float4*)&Xs[kc][8 * tm + 4];  // wave-broadcast
            float xv[8] = {xa.x, xa.y, xa.z, xa.w, xb.x, xb.y, xb.z, xb.w};
            float wvv[4] = {wv.x, wv.y, wv.z, wv.w};
            #pragma unroll
            for (int mi = 0; mi < 8; ++mi)
                #pragma unroll
                for (int ni = 0; ni < 4; ++ni)
                    acc[mi][ni] = fmaf(xv[mi], wvv[ni], acc[mi][ni]);
        }
        __syncthreads();
        wrow += KC;
        xrow += KC;
    }

    float scale = 1.0f;
    if (hz) {
        float h = (float)hz[0] * 0.001f;
        scale = fminf(fmaxf(h, 0.1f), 1.0f);
    }
    const bool addb = (bias != nullptr) && (blockIdx.y == 0);
    #pragma unroll
    for (int mi = 0; mi < 8; ++mi) {
        int m = 8 * tm + mi;
        if (m < NROW) {
            #pragma unroll
            for (int ni = 0; ni < 4; ++ni) {
                int n = n0 + 4 * tn + ni;
                float v = acc[mi][ni];
                if (addb) v += bias[n];
                atomicAdd(&C[(size_t)m * Ntot + n], v * scale);
            }
        }
    }
}

// ---------------------------------------------------------------------------
// col[i] = node_flat[i]·w_n ; row[i] = hist_flat[i]·w_h   (cr[0:27]=col, cr[27:54]=row)
// ---------------------------------------------------------------------------
__global__ __launch_bounds__(256)
void colrow_kernel(const float* __restrict__ node, const float* __restrict__ hist,
                   const float* __restrict__ gw, float* __restrict__ cr)
{
    const int b = blockIdx.x;
    const float* x = (b < NROW) ? node + (size_t)b * EDIM : hist + (size_t)(b - NROW) * EDIM;
    const float* w = (b < NROW) ? gw + EDIM : gw;  // col uses w_n = gw[E:2E], row uses w_h = gw[0:E]
    const int tid = threadIdx.x;
    float a = 0.f;
    for (int f = tid; f < EDIM / 4; f += 256) {
        float4 xv = ((const float4*)x)[f];
        float4 wv = ((const float4*)w)[f];
        a += xv.x * wv.x + xv.y * wv.y + xv.z * wv.z + xv.w * wv.w;
    }
    #pragma unroll
    for (int off = 32; off; off >>= 1) a += __shfl_down(a, off);
    __shared__ float red[4];
    if ((tid & 63) == 0) red[tid >> 6] = a;
    __syncthreads();
    if (tid == 0) cr[b] = red[0] + red[1] + red[2] + red[3];
}

__global__ void adj_kernel(const float* __restrict__ cr, const float* __restrict__ gb,
                           float* __restrict__ adj)
{
    const int t = threadIdx.x;
    if (t < NROW * NROW) {
        const int i = t / NROW, j = t % NROW;
        float v = 0.f;
        if (i != j) {
            float z = cr[i] + cr[NROW + j] + gb[0];
            v = 1.0f / (1.0f + expf(-z));
        }
        adj[t] = v;
    }
}

// ---------------------------------------------------------------------------
// MHA on qkv_f[27, 15360] (biases already folded in by the qkv GEMM).
// One block per (head, query i). H=4, hd=1280.
// ---------------------------------------------------------------------------
__global__ __launch_bounds__(256)
void attn_kernel(const float* __restrict__ qkv, float* __restrict__ O)
{
    __shared__ float qs[HD];
    __shared__ float sc[NROW];
    __shared__ float pr[NROW];
    const int bx = blockIdx.x;
    const int h = bx & 3;
    const int i = bx >> 2;
    const int tid = threadIdx.x;

    const size_t qoff = (size_t)i * QKVDIM + (size_t)h * HD;
    for (int d = tid; d < HD; d += 256) qs[d] = qkv[qoff + d];
    __syncthreads();

    const int wid = tid >> 6, lane = tid & 63;
    for (int j = wid; j < NROW; j += 4) {
        const float* kr = qkv + (size_t)j * QKVDIM + EDIM + (size_t)h * HD;
        float a = 0.f;
        #pragma unroll
        for (int it = 0; it < 5; ++it) {
            int d4 = lane + 64 * it;
            float4 k4 = *(const float4*)(kr + 4 * d4);
            float4 q4 = *(const float4*)(qs + 4 * d4);
            a += q4.x * k4.x + q4.y * k4.y + q4.z * k4.z + q4.w * k4.w;
        }
        #pragma unroll
        for (int off = 32; off; off >>= 1) a += __shfl_down(a, off);
        if (lane == 0) sc[j] = a * 0.02795084971874737f;  // 1/sqrt(1280)
    }
    __syncthreads();

    float mxv = -1e30f;
    for (int j = 0; j < NROW; ++j) mxv = fmaxf(mxv, sc[j]);
    float s = 0.f;
    for (int j = 0; j < NROW; ++j) s += expf(sc[j] - mxv);
    if (tid < NROW) pr[tid] = expf(sc[tid] - mxv) / s;
    __syncthreads();

    for (int d4 = tid; d4 < HD / 4; d4 += 256) {
        float4 o = make_float4(0.f, 0.f, 0.f, 0.f);
        for (int j = 0; j < NROW; ++j) {
            const float4 v4 = *(const float4*)(qkv + (size_t)j * QKVDIM + 2 * EDIM + (size_t)h * HD + 4 * d4);
            const float p = pr[j];
            o.x = fmaf(p, v4.x, o.x);
            o.y = fmaf(p, v4.y, o.y);
            o.z = fmaf(p, v4.z, o.z);
            o.w = fmaf(p, v4.w, o.w);
        }
        *(float4*)(O + (size_t)i * EDIM + (size_t)h * HD + 4 * d4) = o;
    }
}

extern "C" void kernel_launch(void* const* d_in, const int* in_sizes, int n_in,
                              void* d_out, int out_size, void* d_ws, size_t ws_size,
                              hipStream_t stream)
{
    const float* node = (const float*)d_in[0];
    const float* hist = (const float*)d_in[1];
    const float* gw   = (const float*)d_in[2];
    const float* gb   = (const float*)d_in[3];
    const float* inw  = (const float*)d_in[4];
    const float* inb  = (const float*)d_in[5];
    const float* outw = (const float*)d_in[6];
    const float* outb = (const float*)d_in[7];
    const int*   hz   = (const int*)d_in[8];

    float* out  = (float*)d_out;                 // [0:138240) attended-out, [138240:138969) adj
    float* qkvf = (float*)d_ws;                  // 27*15360 floats
    float* Obuf = qkvf + (size_t)NROW * QKVDIM;  // 27*5120 floats
    float* cr   = Obuf + (size_t)NROW * EDIM;    // 54 floats

    hipMemsetAsync(qkvf, 0, sizeof(float) * NROW * QKVDIM, stream);
    hipMemsetAsync(out, 0, sizeof(float) * NROW * EDIM, stream);

    colrow_kernel<<<54, 256, 0, stream>>>(node, hist, gw, cr);
    adj_kernel<<<1, 768, 0, stream>>>(cr, gb, out + (size_t)NROW * EDIM);

    // qkv = x @ in_w.T + in_b  -> qkvf
    gemm_tall<<<dim3(60, 8), 256, 0, stream>>>(node, inw, qkvf, inb, nullptr,
                                               EDIM, QKVDIM, EDIM / 8);
    attn_kernel<<<108, 256, 0, stream>>>(qkvf, Obuf);
    // out = (O @ out_w.T + out_b) * hertz_weight -> d_out (atomic)
    gemm_tall<<<dim3(20, 16), 256, 0, stream>>>(Obuf, outw, out, outb, hz,
                                                EDIM, EDIM, EDIM / 16);
}

// Round 2
// 550.167 us; speedup vs baseline: 1.1658x; 1.1658x over previous
//
#include <hip/hip_runtime.h>

#define NROW 27
#define EDIM 5120
#define QKVDIM 15360
#define HD 1280

typedef __attribute__((ext_vector_type(8))) short bf16x8;
typedef __attribute__((ext_vector_type(4))) float f32x4;

__device__ inline short f2bf(float x) {
    unsigned u = __builtin_bit_cast(unsigned, x);
    u = (u + 0x7FFFu + ((u >> 16) & 1u)) >> 16;
    return (short)u;
}
__device__ inline float bf2f(short h) {
    unsigned u = ((unsigned)(unsigned short)h) << 16;
    return __builtin_bit_cast(float, u);
}

// ---------------------------------------------------------------------------
// C_partial[ky][27][Ntot] = X[27,K(blk)] @ W[Ntot,K(blk)]^T via bf16 hi/lo
// split MFMA (fp32-level accuracy: Ahi*Bhi + Ahi*Blo + Alo*Bhi).
// Block: Ntile=128, Mtile=32(27 real), KC=64 per chunk, 256 thr = 4 waves,
// wave w owns n-subrange [32w,32w+32): 2x2 tiles of 16x16x32 MFMA.
// No atomics: blockIdx.y writes its own partial slice; reduce kernel sums.
// ---------------------------------------------------------------------------
#define KC 64
#define LDK 72   // k-stride in shorts (64 + 8 pad -> 144 B rows, 16B aligned)

__global__ __launch_bounds__(256)
void gemm_bf16x2(const float* __restrict__ X, const float* __restrict__ W,
                 float* __restrict__ Cp, int K, int Ntot, int Kblk)
{
    __shared__ short Whi[128][LDK];   // 18.4 KB
    __shared__ short Wlo[128][LDK];   // 18.4 KB
    __shared__ short Xhi[32][LDK];    // 4.6 KB
    __shared__ short Xlo[32][LDK];    // 4.6 KB

    const int tid = threadIdx.x;
    const int n0 = blockIdx.x * 128;
    const int k0 = blockIdx.y * Kblk;

    const int lane = tid & 63;
    const int wv   = tid >> 6;        // wave id 0..3
    const int lm   = lane & 15;
    const int q8   = (lane >> 4) * 8; // quad*8 (A/B fragment k-offset)

    f32x4 acc[2][2] = {};

    // W loader: 2 threads per row, 32 floats each (8 float4, 128B contiguous)
    const int wr  = tid >> 1;
    const int wkh = (tid & 1) * 32;
    const float* wp = W + (size_t)(n0 + wr) * K + k0 + wkh;

    // X loader: 8 threads per row, 8 floats each
    const int xr = tid >> 3;
    const int xk = (tid & 7) * 8;
    const bool xok = (xr < NROW);
    const float* xp = X + (size_t)(xok ? xr : 0) * K + k0 + xk;

    for (int kc = 0; kc < Kblk; kc += KC) {
        // ---- stage W (fp32 -> bf16 hi/lo) ----
        float wbuf[32];
        #pragma unroll
        for (int i = 0; i < 8; ++i)
            *(float4*)&wbuf[4 * i] = ((const float4*)wp)[i];
        #pragma unroll
        for (int g = 0; g < 4; ++g) {
            bf16x8 h8, l8;
            #pragma unroll
            for (int j = 0; j < 8; ++j) {
                float f = wbuf[8 * g + j];
                short h = f2bf(f);
                h8[j] = h;
                l8[j] = f2bf(f - bf2f(h));
            }
            *(bf16x8*)&Whi[wr][wkh + 8 * g] = h8;
            *(bf16x8*)&Wlo[wr][wkh + 8 * g] = l8;
        }
        // ---- stage X ----
        {
            float xbuf[8];
            if (xok) {
                *(float4*)&xbuf[0] = ((const float4*)xp)[0];
                *(float4*)&xbuf[4] = ((const float4*)xp)[1];
            } else {
                #pragma unroll
                for (int j = 0; j < 8; ++j) xbuf[j] = 0.f;
            }
            bf16x8 h8, l8;
            #pragma unroll
            for (int j = 0; j < 8; ++j) {
                short h = f2bf(xbuf[j]);
                h8[j] = h;
                l8[j] = f2bf(xbuf[j] - bf2f(h));
            }
            *(bf16x8*)&Xhi[xr][xk] = h8;
            *(bf16x8*)&Xlo[xr][xk] = l8;
        }
        __syncthreads();

        #pragma unroll
        for (int s = 0; s < 2; ++s) {
            const int ko = 32 * s + q8;
            bf16x8 ah0 = *(const bf16x8*)&Xhi[lm][ko];
            bf16x8 ah1 = *(const bf16x8*)&Xhi[lm + 16][ko];
            bf16x8 al0 = *(const bf16x8*)&Xlo[lm][ko];
            bf16x8 al1 = *(const bf16x8*)&Xlo[lm + 16][ko];
            bf16x8 bh0 = *(const bf16x8*)&Whi[32 * wv + lm][ko];
            bf16x8 bh1 = *(const bf16x8*)&Whi[32 * wv + 16 + lm][ko];
            bf16x8 bl0 = *(const bf16x8*)&Wlo[32 * wv + lm][ko];
            bf16x8 bl1 = *(const bf16x8*)&Wlo[32 * wv + 16 + lm][ko];

            acc[0][0] = __builtin_amdgcn_mfma_f32_16x16x32_bf16(ah0, bh0, acc[0][0], 0, 0, 0);
            acc[0][0] = __builtin_amdgcn_mfma_f32_16x16x32_bf16(ah0, bl0, acc[0][0], 0, 0, 0);
            acc[0][0] = __builtin_amdgcn_mfma_f32_16x16x32_bf16(al0, bh0, acc[0][0], 0, 0, 0);

            acc[0][1] = __builtin_amdgcn_mfma_f32_16x16x32_bf16(ah0, bh1, acc[0][1], 0, 0, 0);
            acc[0][1] = __builtin_amdgcn_mfma_f32_16x16x32_bf16(ah0, bl1, acc[0][1], 0, 0, 0);
            acc[0][1] = __builtin_amdgcn_mfma_f32_16x16x32_bf16(al0, bh1, acc[0][1], 0, 0, 0);

            acc[1][0] = __builtin_amdgcn_mfma_f32_16x16x32_bf16(ah1, bh0, acc[1][0], 0, 0, 0);
            acc[1][0] = __builtin_amdgcn_mfma_f32_16x16x32_bf16(ah1, bl0, acc[1][0], 0, 0, 0);
            acc[1][0] = __builtin_amdgcn_mfma_f32_16x16x32_bf16(al1, bh0, acc[1][0], 0, 0, 0);

            acc[1][1] = __builtin_amdgcn_mfma_f32_16x16x32_bf16(ah1, bh1, acc[1][1], 0, 0, 0);
            acc[1][1] = __builtin_amdgcn_mfma_f32_16x16x32_bf16(ah1, bl1, acc[1][1], 0, 0, 0);
            acc[1][1] = __builtin_amdgcn_mfma_f32_16x16x32_bf16(al1, bh1, acc[1][1], 0, 0, 0);
        }
        __syncthreads();
        wp += KC;
        xp += KC;
    }

    // ---- epilogue: write partials (C/D layout: col=lane&15, row=quad*4+reg) ----
    const size_t base = (size_t)blockIdx.y * NROW * Ntot;
    #pragma unroll
    for (int mi = 0; mi < 2; ++mi) {
        #pragma unroll
        for (int r = 0; r < 4; ++r) {
            const int m = mi * 16 + (lane >> 4) * 4 + r;
            if (m < NROW) {
                #pragma unroll
                for (int ni = 0; ni < 2; ++ni) {
                    const int n = n0 + 32 * wv + ni * 16 + lm;
                    Cp[base + (size_t)m * Ntot + n] = acc[mi][ni][r];
                }
            }
        }
    }
}

// ---------------------------------------------------------------------------
// out[27,Ntot] = sum_ky Cp[ky] + bias, optionally * hertz clip scale
// ---------------------------------------------------------------------------
__global__ __launch_bounds__(256)
void reduce_kernel(const float* __restrict__ Cp, const float* __restrict__ bias,
                   float* __restrict__ out, int Ntot, int nky, const int* __restrict__ hz)
{
    const int idx = blockIdx.x * 256 + threadIdx.x;  // float4 index
    const int total4 = NROW * Ntot / 4;
    if (idx >= total4) return;
    float4 s = ((const float4*)Cp)[idx];
    for (int k = 1; k < nky; ++k) {
        float4 p = ((const float4*)(Cp + (size_t)k * NROW * Ntot))[idx];
        s.x += p.x; s.y += p.y; s.z += p.z; s.w += p.w;
    }
    const int n = (idx * 4) % Ntot;
    float4 b = *(const float4*)(bias + n);
    s.x += b.x; s.y += b.y; s.z += b.z; s.w += b.w;
    if (hz) {
        float h = (float)hz[0] * 0.001f;
        float sc = fminf(fmaxf(h, 0.1f), 1.0f);
        s.x *= sc; s.y *= sc; s.z *= sc; s.w *= sc;
    }
    ((float4*)out)[idx] = s;
}

// ---------------------------------------------------------------------------
// col[i] = node_flat[i]·w_n ; row[i] = hist_flat[i]·w_h
// ---------------------------------------------------------------------------
__global__ __launch_bounds__(256)
void colrow_kernel(const float* __restrict__ node, const float* __restrict__ hist,
                   const float* __restrict__ gw, float* __restrict__ cr)
{
    const int b = blockIdx.x;
    const float* x = (b < NROW) ? node + (size_t)b * EDIM : hist + (size_t)(b - NROW) * EDIM;
    const float* w = (b < NROW) ? gw + EDIM : gw;
    const int tid = threadIdx.x;
    float a = 0.f;
    for (int f = tid; f < EDIM / 4; f += 256) {
        float4 xv = ((const float4*)x)[f];
        float4 wv = ((const float4*)w)[f];
        a += xv.x * wv.x + xv.y * wv.y + xv.z * wv.z + xv.w * wv.w;
    }
    #pragma unroll
    for (int off = 32; off; off >>= 1) a += __shfl_down(a, off);
    __shared__ float red[4];
    if ((tid & 63) == 0) red[tid >> 6] = a;
    __syncthreads();
    if (tid == 0) cr[b] = red[0] + red[1] + red[2] + red[3];
}

__global__ void adj_kernel(const float* __restrict__ cr, const float* __restrict__ gb,
                           float* __restrict__ adj)
{
    const int t = threadIdx.x;
    if (t < NROW * NROW) {
        const int i = t / NROW, j = t % NROW;
        float v = 0.f;
        if (i != j) {
            float z = cr[i] + cr[NROW + j] + gb[0];
            v = 1.0f / (1.0f + expf(-z));
        }
        adj[t] = v;
    }
}

// ---------------------------------------------------------------------------
// MHA on qkv[27, 15360] (biases already added). One block per (head, query).
// ---------------------------------------------------------------------------
__global__ __launch_bounds__(256)
void attn_kernel(const float* __restrict__ qkv, float* __restrict__ O)
{
    __shared__ float qs[HD];
    __shared__ float sc[NROW];
    __shared__ float pr[NROW];
    const int bx = blockIdx.x;
    const int h = bx & 3;
    const int i = bx >> 2;
    const int tid = threadIdx.x;

    const size_t qoff = (size_t)i * QKVDIM + (size_t)h * HD;
    for (int d = tid; d < HD; d += 256) qs[d] = qkv[qoff + d];
    __syncthreads();

    const int wid = tid >> 6, lane = tid & 63;
    for (int j = wid; j < NROW; j += 4) {
        const float* kr = qkv + (size_t)j * QKVDIM + EDIM + (size_t)h * HD;
        float a = 0.f;
        #pragma unroll
        for (int it = 0; it < 5; ++it) {
            int d4 = lane + 64 * it;
            float4 k4 = *(const float4*)(kr + 4 * d4);
            float4 q4 = *(const float4*)(qs + 4 * d4);
            a += q4.x * k4.x + q4.y * k4.y + q4.z * k4.z + q4.w * k4.w;
        }
        #pragma unroll
        for (int off = 32; off; off >>= 1) a += __shfl_down(a, off);
        if (lane == 0) sc[j] = a * 0.02795084971874737f;  // 1/sqrt(1280)
    }
    __syncthreads();

    float mxv = -1e30f;
    for (int j = 0; j < NROW; ++j) mxv = fmaxf(mxv, sc[j]);
    float s = 0.f;
    for (int j = 0; j < NROW; ++j) s += expf(sc[j] - mxv);
    if (tid < NROW) pr[tid] = expf(sc[tid] - mxv) / s;
    __syncthreads();

    for (int d4 = tid; d4 < HD / 4; d4 += 256) {
        float4 o = make_float4(0.f, 0.f, 0.f, 0.f);
        for (int j = 0; j < NROW; ++j) {
            const float4 v4 = *(const float4*)(qkv + (size_t)j * QKVDIM + 2 * EDIM + (size_t)h * HD + 4 * d4);
            const float p = pr[j];
            o.x = fmaf(p, v4.x, o.x);
            o.y = fmaf(p, v4.y, o.y);
            o.z = fmaf(p, v4.z, o.z);
            o.w = fmaf(p, v4.w, o.w);
        }
        *(float4*)(O + (size_t)i * EDIM + (size_t)h * HD + 4 * d4) = o;
    }
}

extern "C" void kernel_launch(void* const* d_in, const int* in_sizes, int n_in,
                              void* d_out, int out_size, void* d_ws, size_t ws_size,
                              hipStream_t stream)
{
    const float* node = (const float*)d_in[0];
    const float* hist = (const float*)d_in[1];
    const float* gw   = (const float*)d_in[2];
    const float* gb   = (const float*)d_in[3];
    const float* inw  = (const float*)d_in[4];
    const float* inb  = (const float*)d_in[5];
    const float* outw = (const float*)d_in[6];
    const float* outb = (const float*)d_in[7];
    const int*   hz   = (const int*)d_in[8];

    float* out = (float*)d_out;  // [0:138240) attended-out, [138240:138969) adj

    // ws layout (floats)
    float* Cp1  = (float*)d_ws;                          // 4 * 27 * 15360
    float* qkvf = Cp1 + (size_t)4 * NROW * QKVDIM;       // 27 * 15360
    float* Obuf = qkvf + (size_t)NROW * QKVDIM;          // 27 * 5120
    float* Cp2  = Obuf + (size_t)NROW * EDIM;            // 8 * 27 * 5120
    float* cr   = Cp2 + (size_t)8 * NROW * EDIM;         // 54

    colrow_kernel<<<54, 256, 0, stream>>>(node, hist, gw, cr);
    adj_kernel<<<1, 768, 0, stream>>>(cr, gb, out + (size_t)NROW * EDIM);

    // qkv = node_flat @ in_w.T (+bias in reduce): N=15360, ksplit=4
    gemm_bf16x2<<<dim3(120, 4), 256, 0, stream>>>(node, inw, Cp1, EDIM, QKVDIM, EDIM / 4);
    reduce_kernel<<<(NROW * QKVDIM / 4 + 255) / 256, 256, 0, stream>>>(Cp1, inb, qkvf, QKVDIM, 4, nullptr);

    attn_kernel<<<108, 256, 0, stream>>>(qkvf, Obuf);

    // out = (O @ out_w.T + out_b) * hertz: N=5120, ksplit=8
    gemm_bf16x2<<<dim3(40, 8), 256, 0, stream>>>(Obuf, outw, Cp2, EDIM, EDIM, EDIM / 8);
    reduce_kernel<<<(NROW * EDIM / 4 + 255) / 256, 256, 0, stream>>>(Cp2, outb, out, EDIM, 8, hz);
}

// Round 3
// 540.062 us; speedup vs baseline: 1.1877x; 1.0187x over previous
//
#include <hip/hip_runtime.h>

#define NROW 27
#define EDIM 5120
#define QKVDIM 15360
#define HD 1280

typedef __attribute__((ext_vector_type(8))) short bf16x8;
typedef __attribute__((ext_vector_type(4))) float f32x4;

__device__ inline short f2bf(float x) {
    unsigned u = __builtin_bit_cast(unsigned, x);
    u = (u + 0x7FFFu + ((u >> 16) & 1u)) >> 16;
    return (short)u;
}
__device__ inline float bf2f(short h) {
    unsigned u = ((unsigned)(unsigned short)h) << 16;
    return __builtin_bit_cast(float, u);
}

// ---------------------------------------------------------------------------
// C_partial[ky][27][Ntot] = X[27,Kblk] @ W[Ntot,Kblk]^T via bf16 hi/lo split
// MFMA (Ahi*Bhi + Ahi*Blo + Alo*Bhi ~ fp32 accuracy). Register-prefetch
// pipeline: next K-chunk loads issue between the barriers so HBM latency
// overlaps the MFMA section (plain VGPR loads don't drain at s_barrier).
// Block: Ntile=128 x Mtile=32(27), KC=64/chunk, 256 thr = 4 waves,
// wave w owns n in [32w, 32w+32): 2x2 tiles of 16x16x32 MFMA.
// ---------------------------------------------------------------------------
#define KC 64
#define LDK 72   // 64 + 8 pad shorts -> 144 B rows (16B-aligned, 2-way banks = free)

__device__ inline void loadW8(float* wbuf, const float* wp) {
    #pragma unroll
    for (int i = 0; i < 8; ++i)
        *(float4*)&wbuf[4 * i] = ((const float4*)wp)[i];
}
__device__ inline void loadX2(float* xbuf, const float* xp, bool xok) {
    if (xok) {
        *(float4*)&xbuf[0] = ((const float4*)xp)[0];
        *(float4*)&xbuf[4] = ((const float4*)xp)[1];
    } else {
        #pragma unroll
        for (int j = 0; j < 8; ++j) xbuf[j] = 0.f;
    }
}

__global__ __launch_bounds__(256)
void gemm_bf16x2(const float* __restrict__ X, const float* __restrict__ W,
                 float* __restrict__ Cp, int K, int Ntot, int Kblk)
{
    __shared__ short Whi[128][LDK];
    __shared__ short Wlo[128][LDK];
    __shared__ short Xhi[32][LDK];
    __shared__ short Xlo[32][LDK];

    const int tid = threadIdx.x;
    const int n0 = blockIdx.x * 128;
    const int k0 = blockIdx.y * Kblk;

    const int lane = tid & 63;
    const int wv   = tid >> 6;
    const int lm   = lane & 15;
    const int q8   = (lane >> 4) * 8;

    f32x4 acc[2][2] = {};

    // W loader: 2 threads/row, 32 contiguous floats each
    const int wr  = tid >> 1;
    const int wkh = (tid & 1) * 32;
    const float* wp = W + (size_t)(n0 + wr) * K + k0 + wkh;
    // X loader: 8 threads/row, 8 floats each
    const int xr = tid >> 3;
    const int xk = (tid & 7) * 8;
    const bool xok = (xr < NROW);
    const float* xp = X + (size_t)(xok ? xr : 0) * K + k0 + xk;

    float wbuf[32], xbuf[8];
    loadW8(wbuf, wp);
    loadX2(xbuf, xp, xok);

    for (int kc = 0; kc < Kblk; kc += KC) {
        // ---- stage current chunk from regs (fp32 -> bf16 hi/lo) ----
        #pragma unroll
        for (int g = 0; g < 4; ++g) {
            bf16x8 h8, l8;
            #pragma unroll
            for (int j = 0; j < 8; ++j) {
                float f = wbuf[8 * g + j];
                short h = f2bf(f);
                h8[j] = h;
                l8[j] = f2bf(f - bf2f(h));
            }
            *(bf16x8*)&Whi[wr][wkh + 8 * g] = h8;
            *(bf16x8*)&Wlo[wr][wkh + 8 * g] = l8;
        }
        {
            bf16x8 h8, l8;
            #pragma unroll
            for (int j = 0; j < 8; ++j) {
                short h = f2bf(xbuf[j]);
                h8[j] = h;
                l8[j] = f2bf(xbuf[j] - bf2f(h));
            }
            *(bf16x8*)&Xhi[xr][xk] = h8;
            *(bf16x8*)&Xlo[xr][xk] = l8;
        }
        __syncthreads();

        // ---- prefetch next chunk into regs (overlaps MFMA below) ----
        if (kc + KC < Kblk) {
            wp += KC; xp += KC;
            loadW8(wbuf, wp);
            loadX2(xbuf, xp, xok);
        }

        // ---- MFMA on staged chunk ----
        #pragma unroll
        for (int s = 0; s < 2; ++s) {
            const int ko = 32 * s + q8;
            bf16x8 ah0 = *(const bf16x8*)&Xhi[lm][ko];
            bf16x8 ah1 = *(const bf16x8*)&Xhi[lm + 16][ko];
            bf16x8 al0 = *(const bf16x8*)&Xlo[lm][ko];
            bf16x8 al1 = *(const bf16x8*)&Xlo[lm + 16][ko];
            bf16x8 bh0 = *(const bf16x8*)&Whi[32 * wv + lm][ko];
            bf16x8 bh1 = *(const bf16x8*)&Whi[32 * wv + 16 + lm][ko];
            bf16x8 bl0 = *(const bf16x8*)&Wlo[32 * wv + lm][ko];
            bf16x8 bl1 = *(const bf16x8*)&Wlo[32 * wv + 16 + lm][ko];

            acc[0][0] = __builtin_amdgcn_mfma_f32_16x16x32_bf16(ah0, bh0, acc[0][0], 0, 0, 0);
            acc[0][0] = __builtin_amdgcn_mfma_f32_16x16x32_bf16(ah0, bl0, acc[0][0], 0, 0, 0);
            acc[0][0] = __builtin_amdgcn_mfma_f32_16x16x32_bf16(al0, bh0, acc[0][0], 0, 0, 0);

            acc[0][1] = __builtin_amdgcn_mfma_f32_16x16x32_bf16(ah0, bh1, acc[0][1], 0, 0, 0);
            acc[0][1] = __builtin_amdgcn_mfma_f32_16x16x32_bf16(ah0, bl1, acc[0][1], 0, 0, 0);
            acc[0][1] = __builtin_amdgcn_mfma_f32_16x16x32_bf16(al0, bh1, acc[0][1], 0, 0, 0);

            acc[1][0] = __builtin_amdgcn_mfma_f32_16x16x32_bf16(ah1, bh0, acc[1][0], 0, 0, 0);
            acc[1][0] = __builtin_amdgcn_mfma_f32_16x16x32_bf16(ah1, bl0, acc[1][0], 0, 0, 0);
            acc[1][0] = __builtin_amdgcn_mfma_f32_16x16x32_bf16(al1, bh0, acc[1][0], 0, 0, 0);

            acc[1][1] = __builtin_amdgcn_mfma_f32_16x16x32_bf16(ah1, bh1, acc[1][1], 0, 0, 0);
            acc[1][1] = __builtin_amdgcn_mfma_f32_16x16x32_bf16(ah1, bl1, acc[1][1], 0, 0, 0);
            acc[1][1] = __builtin_amdgcn_mfma_f32_16x16x32_bf16(al1, bh1, acc[1][1], 0, 0, 0);
        }
        __syncthreads();
    }

    const size_t base = (size_t)blockIdx.y * NROW * Ntot;
    #pragma unroll
    for (int mi = 0; mi < 2; ++mi) {
        #pragma unroll
        for (int r = 0; r < 4; ++r) {
            const int m = mi * 16 + (lane >> 4) * 4 + r;
            if (m < NROW) {
                #pragma unroll
                for (int ni = 0; ni < 2; ++ni) {
                    const int n = n0 + 32 * wv + ni * 16 + lm;
                    Cp[base + (size_t)m * Ntot + n] = acc[mi][ni][r];
                }
            }
        }
    }
}

// ---------------------------------------------------------------------------
// out[27,Ntot] = sum_ky Cp[ky] + bias [, * hertz]; optional fused adj block.
// ---------------------------------------------------------------------------
__global__ __launch_bounds__(256)
void reduce_kernel(const float* __restrict__ Cp, const float* __restrict__ bias,
                   float* __restrict__ out, int Ntot, int nky, const int* __restrict__ hz,
                   const float* __restrict__ cr, const float* __restrict__ gb,
                   float* __restrict__ adj)
{
    if (adj && blockIdx.x == gridDim.x - 1) {
        for (int t = threadIdx.x; t < NROW * NROW; t += 256) {
            const int i = t / NROW, j = t % NROW;
            float v = 0.f;
            if (i != j) {
                float z = cr[i] + cr[NROW + j] + gb[0];
                v = 1.0f / (1.0f + expf(-z));
            }
            adj[t] = v;
        }
        return;
    }
    const int idx = blockIdx.x * 256 + threadIdx.x;  // float4 index
    const int total4 = NROW * Ntot / 4;
    if (idx >= total4) return;
    float4 s = ((const float4*)Cp)[idx];
    for (int k = 1; k < nky; ++k) {
        float4 p = ((const float4*)(Cp + (size_t)k * NROW * Ntot))[idx];
        s.x += p.x; s.y += p.y; s.z += p.z; s.w += p.w;
    }
    const int n = (idx * 4) % Ntot;
    float4 b = *(const float4*)(bias + n);
    s.x += b.x; s.y += b.y; s.z += b.z; s.w += b.w;
    if (hz) {
        float h = (float)hz[0] * 0.001f;
        float sc = fminf(fmaxf(h, 0.1f), 1.0f);
        s.x *= sc; s.y *= sc; s.z *= sc; s.w *= sc;
    }
    ((float4*)out)[idx] = s;
}

// ---------------------------------------------------------------------------
// col[i] = node_flat[i]·w_n ; row[i] = hist_flat[i]·w_h
// ---------------------------------------------------------------------------
__global__ __launch_bounds__(256)
void colrow_kernel(const float* __restrict__ node, const float* __restrict__ hist,
                   const float* __restrict__ gw, float* __restrict__ cr)
{
    const int b = blockIdx.x;
    const float* x = (b < NROW) ? node + (size_t)b * EDIM : hist + (size_t)(b - NROW) * EDIM;
    const float* w = (b < NROW) ? gw + EDIM : gw;
    const int tid = threadIdx.x;
    float a = 0.f;
    for (int f = tid; f < EDIM / 4; f += 256) {
        float4 xv = ((const float4*)x)[f];
        float4 wv = ((const float4*)w)[f];
        a += xv.x * wv.x + xv.y * wv.y + xv.z * wv.z + xv.w * wv.w;
    }
    #pragma unroll
    for (int off = 32; off; off >>= 1) a += __shfl_down(a, off);
    __shared__ float red[4];
    if ((tid & 63) == 0) red[tid >> 6] = a;
    __syncthreads();
    if (tid == 0) cr[b] = red[0] + red[1] + red[2] + red[3];
}

// ---------------------------------------------------------------------------
// MHA on qkv[27, 15360] (biases already added). One block per (head, query).
// ---------------------------------------------------------------------------
__global__ __launch_bounds__(256)
void attn_kernel(const float* __restrict__ qkv, float* __restrict__ O)
{
    __shared__ float qs[HD];
    __shared__ float sc[NROW];
    __shared__ float pr[NROW];
    const int bx = blockIdx.x;
    const int h = bx & 3;
    const int i = bx >> 2;
    const int tid = threadIdx.x;

    const size_t qoff = (size_t)i * QKVDIM + (size_t)h * HD;
    for (int d = tid; d < HD; d += 256) qs[d] = qkv[qoff + d];
    __syncthreads();

    const int wid = tid >> 6, lane = tid & 63;
    for (int j = wid; j < NROW; j += 4) {
        const float* kr = qkv + (size_t)j * QKVDIM + EDIM + (size_t)h * HD;
        float a = 0.f;
        #pragma unroll
        for (int it = 0; it < 5; ++it) {
            int d4 = lane + 64 * it;
            float4 k4 = *(const float4*)(kr + 4 * d4);
            float4 q4 = *(const float4*)(qs + 4 * d4);
            a += q4.x * k4.x + q4.y * k4.y + q4.z * k4.z + q4.w * k4.w;
        }
        #pragma unroll
        for (int off = 32; off; off >>= 1) a += __shfl_down(a, off);
        if (lane == 0) sc[j] = a * 0.02795084971874737f;  // 1/sqrt(1280)
    }
    __syncthreads();

    float mxv = -1e30f;
    for (int j = 0; j < NROW; ++j) mxv = fmaxf(mxv, sc[j]);
    float s = 0.f;
    for (int j = 0; j < NROW; ++j) s += expf(sc[j] - mxv);
    if (tid < NROW) pr[tid] = expf(sc[tid] - mxv) / s;
    __syncthreads();

    for (int d4 = tid; d4 < HD / 4; d4 += 256) {
        float4 o = make_float4(0.f, 0.f, 0.f, 0.f);
        for (int j = 0; j < NROW; ++j) {
            const float4 v4 = *(const float4*)(qkv + (size_t)j * QKVDIM + 2 * EDIM + (size_t)h * HD + 4 * d4);
            const float p = pr[j];
            o.x = fmaf(p, v4.x, o.x);
            o.y = fmaf(p, v4.y, o.y);
            o.z = fmaf(p, v4.z, o.z);
            o.w = fmaf(p, v4.w, o.w);
        }
        *(float4*)(O + (size_t)i * EDIM + (size_t)h * HD + 4 * d4) = o;
    }
}

extern "C" void kernel_launch(void* const* d_in, const int* in_sizes, int n_in,
                              void* d_out, int out_size, void* d_ws, size_t ws_size,
                              hipStream_t stream)
{
    const float* node = (const float*)d_in[0];
    const float* hist = (const float*)d_in[1];
    const float* gw   = (const float*)d_in[2];
    const float* gb   = (const float*)d_in[3];
    const float* inw  = (const float*)d_in[4];
    const float* inb  = (const float*)d_in[5];
    const float* outw = (const float*)d_in[6];
    const float* outb = (const float*)d_in[7];
    const int*   hz   = (const int*)d_in[8];

    float* out = (float*)d_out;  // [0:138240) attended-out, [138240:138969) adj

    // ws layout (floats)
    float* Cp1  = (float*)d_ws;                          // 8 * 27 * 15360
    float* qkvf = Cp1 + (size_t)8 * NROW * QKVDIM;       // 27 * 15360
    float* Obuf = qkvf + (size_t)NROW * QKVDIM;          // 27 * 5120
    float* Cp2  = Obuf + (size_t)NROW * EDIM;            // 16 * 27 * 5120
    float* cr   = Cp2 + (size_t)16 * NROW * EDIM;        // 54

    colrow_kernel<<<54, 256, 0, stream>>>(node, hist, gw, cr);

    // qkv = node_flat @ in_w.T (+bias in reduce): N=15360, ksplit=8
    gemm_bf16x2<<<dim3(120, 8), 256, 0, stream>>>(node, inw, Cp1, EDIM, QKVDIM, EDIM / 8);
    reduce_kernel<<<NROW * QKVDIM / 4 / 256, 256, 0, stream>>>(
        Cp1, inb, qkvf, QKVDIM, 8, nullptr, nullptr, nullptr, nullptr);

    attn_kernel<<<108, 256, 0, stream>>>(qkvf, Obuf);

    // out = (O @ out_w.T + out_b) * hertz: N=5120, ksplit=16; +1 block does adj
    gemm_bf16x2<<<dim3(40, 16), 256, 0, stream>>>(Obuf, outw, Cp2, EDIM, EDIM, EDIM / 16);
    reduce_kernel<<<NROW * EDIM / 4 / 256 + 1, 256, 0, stream>>>(
        Cp2, outb, out, EDIM, 16, hz, cr, gb, out + (size_t)NROW * EDIM);
}